// Round 2
// baseline (166.786 us; speedup 1.0000x reference)
//
#include <hip/hip_runtime.h>

typedef unsigned long long u64;
typedef unsigned int u32;
typedef unsigned char u8;

#define IMH 512
#define IMW 512
#define NB 32
#define NPIX (NB*IMH*IMW)            // 8388608
#define WPI  (IMH*(IMW/64))          // 4096 words per image
#define NWORDS (NB*WPI)              // 131072

// ==================================================================
// Kernel 1: quantize + separable Sobel + NMS -> bitpacked masks
// block: 256 threads; tx = tid&7 (8-px x strip), ty = tid>>3 (row grp)
// tile: 64 px wide x 128 rows; grid (8, 4, 32)
// ==================================================================
#define SLDS_W 72    // floats per row: x0-4 .. x0+67
#define SLDS_H 132   // rows y0-2 .. y0+129

__global__ __launch_bounds__(256) void k_sobel_nms(
    const float* __restrict__ labels,
    u8* __restrict__ edgeb,   // strong bytes (init edge state)
    u8* __restrict__ weakb)
{
    __shared__ float simg[SLDS_H][SLDS_W];
    const int tid = threadIdx.x;
    const int tx = tid & 7, ty = tid >> 3;
    const int xw = blockIdx.x, yt = blockIdx.y, bimg = blockIdx.z;
    const int x0 = xw*64, y0 = yt*128;
    const float* img = labels + (size_t)bimg*(IMH*IMW);

    // ---- stage quantized image tile (replicate border) ----
    const bool interior = (xw > 0) && (xw < 7);
    for (int i = tid; i < SLDS_H*18; i += 256) {
        int r = i/18, c4 = i - r*18;
        int gy = y0 - 2 + r; gy = min(max(gy,0), IMH-1);
        int gx = x0 - 4 + 4*c4;
        float4 v;
        if (interior) {
            v = *(const float4*)&img[gy*IMW + gx];
        } else {
            int xa = min(max(gx  ,0),IMW-1), xb = min(max(gx+1,0),IMW-1);
            int xc = min(max(gx+2,0),IMW-1), xd = min(max(gx+3,0),IMW-1);
            const float* row = img + gy*IMW;
            v.x = row[xa]; v.y = row[xb]; v.z = row[xc]; v.w = row[xd];
        }
        v.x = floorf(fminf(fmaxf(v.x,0.f),1.f)*255.f);
        v.y = floorf(fminf(fmaxf(v.y,0.f),1.f)*255.f);
        v.z = floorf(fminf(fmaxf(v.z,0.f),1.f)*255.f);
        v.w = floorf(fminf(fmaxf(v.w,0.f),1.f)*255.f);
        *(float4*)&simg[r][4*c4] = v;
    }
    __syncthreads();

    // ---- per-thread: 8 px wide x 4 rows, rolling separable Sobel ----
    const int rbase = 4*ty;                 // local out-row base (LDS row rbase+2)
    const bool lzero = (xw==0 && tx==0);    // mag at x=-1 must be 0
    const bool rzero = (xw==7 && tx==7);    // mag at x=512 must be 0
    const float T1f = 0.41421356237309503f; // tan 22.5
    const float T2f = 2.4142135623730951f;  // tan 67.5

    float rX[16], rY[16], qA[16], qB[16];
    float mgA[10], mgB[10], mgC[10];
    float t1[14], t2[14];
    float gxr[10], gyr[10];
    float gxb[8], gyb[8];

#define LDROW(DST, R) do { \
    float4 _f0 = *(const float4*)&simg[(R)][8*tx];    \
    float4 _f1 = *(const float4*)&simg[(R)][8*tx+4];  \
    float4 _f2 = *(const float4*)&simg[(R)][8*tx+8];  \
    float4 _f3 = *(const float4*)&simg[(R)][8*tx+12]; \
    DST[0]=_f0.x; DST[1]=_f0.y; DST[2]=_f0.z; DST[3]=_f0.w; \
    DST[4]=_f1.x; DST[5]=_f1.y; DST[6]=_f1.z; DST[7]=_f1.w; \
    DST[8]=_f2.x; DST[9]=_f2.y; DST[10]=_f2.z; DST[11]=_f2.w; \
    DST[12]=_f3.x; DST[13]=_f3.y; DST[14]=_f3.z; DST[15]=_f3.w; \
} while(0)

    LDROW(rX, rbase);       // img row y0+rbase-2
    LDROW(rY, rbase+1);     // img row y0+rbase-1
#pragma unroll
    for (int j=0;j<16;++j) qA[j] = rX[j] + rY[j];

// STEP(S): load next img row into RN; q_new = RL + RN (QN);
// t-row (global y0+rbase+S-1) from QP,QN; mag row into MGT.
#define STEP(S, RN, RL, QP, QN, MGT) do { \
    LDROW(RN, rbase+2+(S)); \
    _Pragma("unroll") \
    for (int j=0;j<16;++j) QN[j] = RL[j] + RN[j]; \
    _Pragma("unroll") \
    for (int j=2;j<14;++j) { t1[j] = QP[j] + QN[j]; t2[j] = QN[j] - QP[j]; } \
    { const int gr = y0 + rbase + (S) - 1; \
      const bool rok = (gr >= 0) && (gr < IMH); \
      _Pragma("unroll") \
      for (int jm=0;jm<10;++jm) { int j=jm+3; \
          gxr[jm] = t1[j+1]-t1[j-1]; \
          gyr[jm] = t2[j-1]+t2[j]+t2[j]+t2[j+1]; \
          float mv = fabsf(gxr[jm])+fabsf(gyr[jm]); \
          MGT[jm] = rok ? mv : 0.f; } \
      if (lzero) MGT[0] = 0.f; \
      if (rzero) MGT[9] = 0.f; } \
} while(0)

// NMS for out row gq = y0+rbase+S-2 using gxb/gyb (filled previous step)
#define DONMS(S, MP, MC, MN) do { \
    u32 sbyte = 0u, wbyte = 0u; \
    _Pragma("unroll") \
    for (int k=0;k<8;++k) { \
        float m   = MC[k+1]; \
        float gx_ = gxb[k], gy_ = gyb[k]; \
        float ax = fabsf(gx_), ay = fabsf(gy_); \
        bool bb0  = ay <  T1f*ax; \
        bool bb90 = ay >= T2f*ax; \
        bool bb45 = (!bb0) && (!bb90) && (gx_*gy_ > 0.f); \
        float n1 = bb0 ? MC[k+2] : (bb45 ? MP[k+2] : (bb90 ? MN[k+1] : MP[k]  )); \
        float n2 = bb0 ? MC[k]   : (bb45 ? MN[k]   : (bb90 ? MP[k+1] : MN[k+2])); \
        bool nms = (m >= n1) && (m >= n2); \
        if (nms && (m > 200.f)) sbyte |= (1u<<k); \
        if (nms && (m > 100.f)) wbyte |= (1u<<k); \
    } \
    const int gq = y0 + rbase + (S) - 2; \
    const size_t bix = (size_t)(bimg*IMH + gq)*64 + xw*8 + tx; \
    edgeb[bix] = (u8)sbyte; weakb[bix] = (u8)wbyte; \
} while(0)

#define GXB() do { \
    _Pragma("unroll") \
    for (int k=0;k<8;++k) { gxb[k]=gxr[k+1]; gyb[k]=gyr[k+1]; } \
} while(0)

    STEP(0, rX, rY, qA, qB, mgA);
    STEP(1, rY, rX, qB, qA, mgB);                        GXB();
    STEP(2, rX, rY, qA, qB, mgC); DONMS(2, mgA, mgB, mgC); GXB();
    STEP(3, rY, rX, qB, qA, mgA); DONMS(3, mgB, mgC, mgA); GXB();
    STEP(4, rX, rY, qA, qB, mgB); DONMS(4, mgC, mgA, mgB); GXB();
    STEP(5, rY, rX, qB, qA, mgC); DONMS(5, mgA, mgB, mgC);
}

// ==================================================================
// Kernel 2: hysteresis, 8 dilate iterations per launch inside LDS.
// Strip: 64 rows x 512 px (+8-row halo). Monotone -> races benign.
// grid: 256 blocks (32 img x 8 strips), 256 threads.
// ==================================================================
#define HROWS 64
#define HHALO 8
#define HLDSR (HROWS + 2*HHALO)   // 80

__device__ inline u64 hz3(u64 l, u64 c, u64 r) {
    return c | (c<<1) | (c>>1) | (l>>63) | (r<<63);
}

__global__ __launch_bounds__(256) void k_hyst(
    u64* __restrict__ edgew,
    const u64* __restrict__ weakw,
    int* __restrict__ flags, int p)
{
    if (p > 0 && flags[p-1] == 0) return;
    __shared__ u64 ed[HLDSR][8];
    __shared__ u64 wk[HLDSR][8];
    const int tid = threadIdx.x;
    const int strip = blockIdx.x & 7, b = blockIdx.x >> 3;
    const int y0 = strip*HROWS;
    u64* ebase = edgew + (size_t)b*WPI;
    const u64* wbase = weakw + (size_t)b*WPI;

    u64 orig[3] = {0,0,0};
#pragma unroll
    for (int k = 0; k < 3; ++k) {
        int w = tid + k*256;
        if (w < HLDSR*8) {
            int r = w >> 3, c = w & 7;
            int gr = y0 - HHALO + r;
            u64 e = 0, ww = 0;
            if (gr >= 0 && gr < IMH) { e = ebase[gr*8+c]; ww = wbase[gr*8+c]; }
            ed[r][c] = e; wk[r][c] = ww;
            orig[k] = e;
        }
    }
    __syncthreads();

    for (int it = 0; it < HHALO; ++it) {
#pragma unroll
        for (int k = 0; k < 3; ++k) {
            int w = tid + k*256;
            if (w < HLDSR*8) {
                int r = w >> 3, c = w & 7;
                u64 cm = ed[r][c];
                u64 lm = (c>0)? ed[r][c-1] : 0, rm = (c<7)? ed[r][c+1] : 0;
                u64 d = hz3(lm, cm, rm);
                if (r > 0) {
                    u64 cu = ed[r-1][c];
                    u64 lu = (c>0)? ed[r-1][c-1] : 0, ru = (c<7)? ed[r-1][c+1] : 0;
                    d |= hz3(lu, cu, ru);
                }
                if (r < HLDSR-1) {
                    u64 cd = ed[r+1][c];
                    u64 ld = (c>0)? ed[r+1][c-1] : 0, rd = (c<7)? ed[r+1][c+1] : 0;
                    d |= hz3(ld, cd, rd);
                }
                ed[r][c] = wk[r][c] & d;
            }
        }
        __syncthreads();
    }

    bool chg = false;
#pragma unroll
    for (int k = 0; k < 3; ++k) {
        int w = tid + k*256;
        if (w < HLDSR*8) {
            int r = w >> 3, c = w & 7;
            if (r >= HHALO && r < HHALO + HROWS) {
                u64 nw = ed[r][c];
                if (nw != orig[k]) {
                    chg = true;
                    ebase[(y0 - HHALO + r)*8 + c] = nw;
                }
            }
        }
    }
    if (chg) flags[p] = 1;
}

// ==================================================================
// Kernel 3: NLL loss sum, float4 + fast softplus, double accumulation
// ==================================================================
__global__ __launch_bounds__(256) void k_loss(
    const float* __restrict__ pred,
    const u64* __restrict__ edgew,
    double* __restrict__ acc)
{
    const int NF4 = NB*65536;     // float4's per channel-0 sweep
    int stride = gridDim.x*256;
    double s = 0.0;
    for (int g = blockIdx.x*256 + threadIdx.x; g < NF4; g += stride) {
        int b = g >> 16, rem4 = g & 65535;
        const float4 p0 = *(const float4*)&pred[((size_t)(2*b)  <<18) + 4*(size_t)rem4];
        const float4 p1 = *(const float4*)&pred[((size_t)(2*b+1)<<18) + 4*(size_t)rem4];
        u64 wrd = edgew[(b<<12) | (rem4>>4)];
        u32 nib = (u32)(wrd >> ((rem4 & 15)*4)) & 0xFu;

        float d0 = p1.x - p0.x, d1 = p1.y - p0.y, d2 = p1.z - p0.z, d3 = p1.w - p0.w;
        float t0_ = (nib & 1u) ? -d0 : d0;
        float t1_ = (nib & 2u) ? -d1 : d1;
        float t2_ = (nib & 4u) ? -d2 : d2;
        float t3_ = (nib & 8u) ? -d3 : d3;
        float sp0 = fmaxf(t0_,0.f) + __logf(1.f + __expf(-fabsf(t0_)));
        float sp1 = fmaxf(t1_,0.f) + __logf(1.f + __expf(-fabsf(t1_)));
        float sp2 = fmaxf(t2_,0.f) + __logf(1.f + __expf(-fabsf(t2_)));
        float sp3 = fmaxf(t3_,0.f) + __logf(1.f + __expf(-fabsf(t3_)));
        s += (double)((sp0 + sp1) + (sp2 + sp3));
    }
    for (int off = 32; off > 0; off >>= 1) s += __shfl_down(s, off);
    __shared__ double ssum[4];
    int lane = threadIdx.x & 63, wv = threadIdx.x >> 6;
    if (lane == 0) ssum[wv] = s;
    __syncthreads();
    if (threadIdx.x == 0) {
        double t = ssum[0] + ssum[1] + ssum[2] + ssum[3];
        atomicAdd(acc, t);
    }
}

__global__ void k_final(const double* __restrict__ acc, float* __restrict__ out) {
    out[0] = (float)(acc[0] * (1.0/8388608.0));
}

// ==================================================================
extern "C" void kernel_launch(void* const* d_in, const int* in_sizes, int n_in,
                              void* d_out, int out_size, void* d_ws, size_t ws_size,
                              hipStream_t stream)
{
    const float* pred   = (const float*)d_in[0];
    const float* labels = (const float*)d_in[1];
    float* out = (float*)d_out;

    char* ws = (char*)d_ws;
    double* acc   = (double*)ws;                    // 8 B
    int*    flags = (int*)(ws + 8);                 // pass flags
    u64*    edgew = (u64*)(ws + 4096);              // 1 MB
    u64*    weakw = edgew + NWORDS;                 // 1 MB

    hipMemsetAsync(ws, 0, 4096, stream);            // zero acc + flags

    k_sobel_nms<<<dim3(8,4,32), 256, 0, stream>>>(labels, (u8*)edgew, (u8*)weakw);

    for (int p = 0; p < 4; ++p)                     // 4 x 8 = 32 dilate steps
        k_hyst<<<256, 256, 0, stream>>>(edgew, weakw, flags, p);

    k_loss<<<8192, 256, 0, stream>>>(pred, edgew, acc);
    k_final<<<1, 1, 0, stream>>>(acc, out);
}

// Round 3
// 93.518 us; speedup vs baseline: 1.7835x; 1.7835x over previous
//
#include <hip/hip_runtime.h>

typedef unsigned long long u64;
typedef unsigned int u32;
typedef unsigned char u8;

#define IMH 512
#define IMW 512
#define NB 32
#define WPI 4096
#define NWORDS (NB*WPI)

#define QZ(v) floorf(fminf(fmaxf((v),0.f),1.f)*255.f)

// ==================================================================
// Kernel 1: register-rolling separable Sobel + NMS, no LDS.
// 1 wave/block; lane owns 4 cols; band = 32 output rows; strip = 256 px.
// grid 1024 = 32 img * 2 strips * 16 bands.
// ==================================================================
#define LOADRAW(Y, V, HL, HR) do { \
    int _yc = (Y); _yc = _yc < 0 ? 0 : (_yc > 511 ? 511 : _yc); \
    const float* _row = img + _yc*IMW; \
    V = *(const float4*)&_row[xb]; \
    if (L0)  HL = *(const float2*)&_row[strip ? (X0-2) : 0]; \
    if (L63) HR = *(const float2*)&_row[strip ? 510 : (X0+256)]; \
} while(0)

#define NMSJ(J, QAm, QA0, QAp, PBm, PB0, PBp, CCm, CC0, CCp) do { \
    float m = PB0; \
    float gx_ = gxP[J], gy_ = gyP[J]; \
    float ax = fabsf(gx_), ay = fabsf(gy_); \
    bool c0_ = ay <  T1f*ax; \
    bool c90 = ay >= T2f*ax; \
    bool c45 = (!c0_) && (!c90) && (gx_*gy_ > 0.f); \
    float n1 = c0_ ? PBp : (c45 ? QAp : (c90 ? CC0 : QAm)); \
    float n2 = c0_ ? PBm : (c45 ? CCm : (c90 ? QA0 : CCp)); \
    if (m >= n1 && m >= n2) { \
        if (m > 100.f) wb |= (1u<<(J)); \
        if (m > 200.f) sb |= (1u<<(J)); \
    } \
} while(0)

#define STEP(Y, VIN, HLIN, HRIN, VNX, HLNX, HRNX, DOLOAD) do { \
    if (DOLOAD) LOADRAW((Y)+1, VNX, HLNX, HRNX); \
    float c0=QZ(VIN.x), c1=QZ(VIN.y), c2=QZ(VIN.z), c3=QZ(VIN.w); \
    float chl0 = QZ(HLIN.x), chl1 = strip ? QZ(HLIN.y) : QZ(HLIN.x); \
    float chr0 = strip ? QZ(HRIN.y) : QZ(HRIN.x), chr1 = QZ(HRIN.y); \
    float qn0=rP[0]+c0, qn1=rP[1]+c1, qn2=rP[2]+c2, qn3=rP[3]+c3; \
    float ql0=hPl0+chl0, ql1=hPl1+chl1, qr0=hPr0+chr0, qr1=hPr1+chr1; \
    float t1_0=qP[0]+qn0, t1_1=qP[1]+qn1, t1_2=qP[2]+qn2, t1_3=qP[3]+qn3; \
    float t2_0=qn0-qP[0], t2_1=qn1-qP[1], t2_2=qn2-qP[2], t2_3=qn3-qP[3]; \
    float t1l0=qPl0+ql0, t2l0=ql0-qPl0, t1l1=qPl1+ql1, t2l1=ql1-qPl1; \
    float t1r0=qPr0+qr0, t2r0=qr0-qPr0, t1r1=qPr1+qr1, t2r1=qr1-qPr1; \
    float su1=__shfl_up(t1_3,1), su2=__shfl_up(t2_3,1); \
    float sd1=__shfl_down(t1_0,1), sd2=__shfl_down(t2_0,1); \
    float t1m = L0 ? t1l1 : su1, t2m = L0 ? t2l1 : su2; \
    float t1p = L63 ? t1r0 : sd1, t2p = L63 ? t2r0 : sd2; \
    const int ry = (Y)-1; \
    const bool rok = (ry >= 0) && (ry <= 511); \
    float gxc0 = t1_1-t1m,  gyc0 = t2m +2.f*t2_0+t2_1; \
    float gxc1 = t1_2-t1_0, gyc1 = t2_0+2.f*t2_1+t2_2; \
    float gxc2 = t1_3-t1_1, gyc2 = t2_1+2.f*t2_2+t2_3; \
    float gxc3 = t1p -t1_2, gyc3 = t2_2+2.f*t2_3+t2p; \
    float mc0 = rok ? fabsf(gxc0)+fabsf(gyc0) : 0.f; \
    float mc1 = rok ? fabsf(gxc1)+fabsf(gyc1) : 0.f; \
    float mc2 = rok ? fabsf(gxc2)+fabsf(gyc2) : 0.f; \
    float mc3 = rok ? fabsf(gxc3)+fabsf(gyc3) : 0.f; \
    float gxl = t1_0-t1l0, gyl = t2l0+2.f*t2l1+t2_0; \
    float gxr = t1r1-t1_3, gyr = t2_3+2.f*t2r0+t2r1; \
    float mlh = (rok && strip!=0) ? fabsf(gxl)+fabsf(gyl) : 0.f; \
    float mrh = (rok && strip!=1) ? fabsf(gxr)+fabsf(gyr) : 0.f; \
    float sum_ = __shfl_up(mc3,1), sdm_ = __shfl_down(mc0,1); \
    float mCL = L0 ? mlh : sum_; \
    float mCR = L63 ? mrh : sdm_; \
    if ((Y) >= y0+2) { \
        u32 sb=0, wb=0; \
        NMSJ(0, mgQL,  mgQ[0], mgQ[1], mgPL,  mgP[0], mgP[1], mCL, mc0, mc1); \
        NMSJ(1, mgQ[0],mgQ[1], mgQ[2], mgP[0],mgP[1], mgP[2], mc0, mc1, mc2); \
        NMSJ(2, mgQ[1],mgQ[2], mgQ[3], mgP[1],mgP[2], mgP[3], mc1, mc2, mc3); \
        NMSJ(3, mgQ[2],mgQ[3], mgQR,   mgP[2],mgP[3], mgPR,   mc2, mc3, mCR); \
        u32 pk = sb | (wb<<8); \
        u32 oth = __shfl_xor(pk, 1); \
        if (!(lane & 1)) { \
            size_t bix = ((size_t)(bimg*IMH + ((Y)-2)))*64 + strip*32 + (lane>>1); \
            edgeb[bix] = (u8)((sb & 0xFu) | ((oth & 0xFu) << 4)); \
            weakb[bix] = (u8)(((pk>>8) & 0xFu) | (((oth>>8) & 0xFu) << 4)); \
        } \
    } \
    mgQ[0]=mgP[0]; mgQ[1]=mgP[1]; mgQ[2]=mgP[2]; mgQ[3]=mgP[3]; \
    mgQL=mgPL; mgQR=mgPR; \
    mgP[0]=mc0; mgP[1]=mc1; mgP[2]=mc2; mgP[3]=mc3; \
    mgPL=mCL; mgPR=mCR; \
    gxP[0]=gxc0; gxP[1]=gxc1; gxP[2]=gxc2; gxP[3]=gxc3; \
    gyP[0]=gyc0; gyP[1]=gyc1; gyP[2]=gyc2; gyP[3]=gyc3; \
    qP[0]=qn0; qP[1]=qn1; qP[2]=qn2; qP[3]=qn3; \
    qPl0=ql0; qPl1=ql1; qPr0=qr0; qPr1=qr1; \
    rP[0]=c0; rP[1]=c1; rP[2]=c2; rP[3]=c3; \
    hPl0=chl0; hPl1=chl1; hPr0=chr0; hPr1=chr1; \
} while(0)

__global__ __launch_bounds__(64) void k_sobel_nms(
    const float* __restrict__ labels,
    u8* __restrict__ edgeb,
    u8* __restrict__ weakb)
{
    const int lane  = threadIdx.x;
    const int bx    = blockIdx.x;
    const int bimg  = bx >> 5;
    const int strip = bx & 1;
    const int band  = (bx >> 1) & 15;
    const int X0 = strip*256;
    const int y0 = band*32;
    const int xb = X0 + 4*lane;
    const bool L0 = (lane==0), L63 = (lane==63);
    const float* img = labels + (size_t)bimg*(IMH*IMW);
    const float T1f = 0.41421356237309503f;   // tan 22.5
    const float T2f = 2.4142135623730951f;    // tan 67.5

    // rolling state
    float rP[4];                   // prev row quantized px
    float hPl0,hPl1,hPr0,hPr1;     // prev row halo px
    float qP[4];                   // vertical pair-sum boundary (y-2,y-1)
    float qPl0,qPl1,qPr0,qPr1;
    float mgQ[4], mgP[4];          // mag rows y-3, y-2
    float mgQL,mgQR,mgPL,mgPR;
    float gxP[4], gyP[4];          // gradients at row y-2

    float4 vA, vB;
    float2 hlA = make_float2(0.f,0.f), hlB = make_float2(0.f,0.f);
    float2 hrA = make_float2(0.f,0.f), hrB = make_float2(0.f,0.f);

    // warmup: rows y0-2, y0-1
    LOADRAW(y0-2, vA, hlA, hrA);
    LOADRAW(y0-1, vB, hlB, hrB);
    {
        float a0=QZ(vA.x), a1=QZ(vA.y), a2=QZ(vA.z), a3=QZ(vA.w);
        float b0=QZ(vB.x), b1=QZ(vB.y), b2=QZ(vB.z), b3=QZ(vB.w);
        qP[0]=a0+b0; qP[1]=a1+b1; qP[2]=a2+b2; qP[3]=a3+b3;
        rP[0]=b0; rP[1]=b1; rP[2]=b2; rP[3]=b3;
        float al0 = QZ(hlA.x), al1 = strip ? QZ(hlA.y) : QZ(hlA.x);
        float ar0 = strip ? QZ(hrA.y) : QZ(hrA.x), ar1 = QZ(hrA.y);
        hPl0 = QZ(hlB.x); hPl1 = strip ? QZ(hlB.y) : QZ(hlB.x);
        hPr0 = strip ? QZ(hrB.y) : QZ(hrB.x); hPr1 = QZ(hrB.y);
        qPl0 = al0 + hPl0; qPl1 = al1 + hPl1;
        qPr0 = ar0 + hPr0; qPr1 = ar1 + hPr1;
    }
#pragma unroll
    for (int j=0;j<4;++j) { mgQ[j]=0.f; mgP[j]=0.f; gxP[j]=0.f; gyP[j]=0.f; }
    mgQL=mgQR=mgPL=mgPR=0.f;

    // prime row y0
    LOADRAW(y0, vA, hlA, hrA);

#pragma unroll 1
    for (int y = y0; y < y0+34; y += 2) {
        STEP(y,   vA, hlA, hrA, vB, hlB, hrB, (y+1 <= y0+33));
        STEP(y+1, vB, hlB, hrB, vA, hlA, hrA, (y+2 <= y0+33));
    }
}

// ==================================================================
// Kernel 2: hysteresis, 8 dilate iterations per launch inside LDS.
// ==================================================================
#define HROWS 64
#define HHALO 8
#define HLDSR (HROWS + 2*HHALO)   // 80

__device__ inline u64 hz3(u64 l, u64 c, u64 r) {
    return c | (c<<1) | (c>>1) | (l>>63) | (r<<63);
}

__global__ __launch_bounds__(256) void k_hyst(
    u64* __restrict__ edgew,
    const u64* __restrict__ weakw,
    int* __restrict__ flags, int p)
{
    if (p > 0 && flags[p-1] == 0) return;
    __shared__ u64 ed[HLDSR][8];
    __shared__ u64 wk[HLDSR][8];
    const int tid = threadIdx.x;
    const int strip = blockIdx.x & 7, b = blockIdx.x >> 3;
    const int y0 = strip*HROWS;
    u64* ebase = edgew + (size_t)b*WPI;
    const u64* wbase = weakw + (size_t)b*WPI;

    u64 orig[3] = {0,0,0};
#pragma unroll
    for (int k = 0; k < 3; ++k) {
        int w = tid + k*256;
        if (w < HLDSR*8) {
            int r = w >> 3, c = w & 7;
            int gr = y0 - HHALO + r;
            u64 e = 0, ww = 0;
            if (gr >= 0 && gr < IMH) { e = ebase[gr*8+c]; ww = wbase[gr*8+c]; }
            ed[r][c] = e; wk[r][c] = ww;
            orig[k] = e;
        }
    }
    __syncthreads();

    for (int it = 0; it < HHALO; ++it) {
#pragma unroll
        for (int k = 0; k < 3; ++k) {
            int w = tid + k*256;
            if (w < HLDSR*8) {
                int r = w >> 3, c = w & 7;
                u64 cm = ed[r][c];
                u64 lm = (c>0)? ed[r][c-1] : 0, rm = (c<7)? ed[r][c+1] : 0;
                u64 d = hz3(lm, cm, rm);
                if (r > 0) {
                    u64 cu = ed[r-1][c];
                    u64 lu = (c>0)? ed[r-1][c-1] : 0, ru = (c<7)? ed[r-1][c+1] : 0;
                    d |= hz3(lu, cu, ru);
                }
                if (r < HLDSR-1) {
                    u64 cd = ed[r+1][c];
                    u64 ld = (c>0)? ed[r+1][c-1] : 0, rd = (c<7)? ed[r+1][c+1] : 0;
                    d |= hz3(ld, cd, rd);
                }
                ed[r][c] = wk[r][c] & d;
            }
        }
        __syncthreads();
    }

    bool chg = false;
#pragma unroll
    for (int k = 0; k < 3; ++k) {
        int w = tid + k*256;
        if (w < HLDSR*8) {
            int r = w >> 3, c = w & 7;
            if (r >= HHALO && r < HHALO + HROWS) {
                u64 nw = ed[r][c];
                if (nw != orig[k]) {
                    chg = true;
                    ebase[(y0 - HHALO + r)*8 + c] = nw;
                }
            }
        }
    }
    if (chg) flags[p] = 1;
}

// ==================================================================
// Kernel 3: NLL loss, 4 float4-pairs/thread, per-block partials
// ==================================================================
__global__ __launch_bounds__(256) void k_loss(
    const float* __restrict__ pred,
    const u64* __restrict__ edgew,
    double* __restrict__ partial)
{
    const int t = blockIdx.x*256 + threadIdx.x;   // 0..524287
    float acc[4];
#pragma unroll
    for (int k = 0; k < 4; ++k) {
        int g = t + k*524288;                     // 0..2097151
        int b = g >> 16, rem4 = g & 65535;
        const float4 p0 = *(const float4*)&pred[((size_t)(2*b)  <<18) + 4*(size_t)rem4];
        const float4 p1 = *(const float4*)&pred[((size_t)(2*b+1)<<18) + 4*(size_t)rem4];
        u64 wrd = edgew[(b<<12) | (rem4>>4)];
        u32 nib = (u32)(wrd >> ((rem4 & 15)*4)) & 0xFu;
        float d0=p1.x-p0.x, d1=p1.y-p0.y, d2=p1.z-p0.z, d3=p1.w-p0.w;
        float t0_ = (nib&1u) ? -d0 : d0;
        float t1_ = (nib&2u) ? -d1 : d1;
        float t2_ = (nib&4u) ? -d2 : d2;
        float t3_ = (nib&8u) ? -d3 : d3;
        float s0 = fmaxf(t0_,0.f) + __logf(1.f + __expf(-fabsf(t0_)));
        float s1 = fmaxf(t1_,0.f) + __logf(1.f + __expf(-fabsf(t1_)));
        float s2 = fmaxf(t2_,0.f) + __logf(1.f + __expf(-fabsf(t2_)));
        float s3 = fmaxf(t3_,0.f) + __logf(1.f + __expf(-fabsf(t3_)));
        acc[k] = (s0+s1)+(s2+s3);
    }
    double s = ((double)acc[0]+(double)acc[1]) + ((double)acc[2]+(double)acc[3]);
#pragma unroll
    for (int off = 32; off > 0; off >>= 1) s += __shfl_down(s, off);
    __shared__ double sh[4];
    if ((threadIdx.x & 63) == 0) sh[threadIdx.x>>6] = s;
    __syncthreads();
    if (threadIdx.x == 0) partial[blockIdx.x] = (sh[0]+sh[1])+(sh[2]+sh[3]);
}

__global__ __launch_bounds__(256) void k_final(
    const double* __restrict__ partial, float* __restrict__ out)
{
    double s = 0.0;
    for (int i = threadIdx.x; i < 2048; i += 256) s += partial[i];
#pragma unroll
    for (int off = 32; off > 0; off >>= 1) s += __shfl_down(s, off);
    __shared__ double sh[4];
    if ((threadIdx.x & 63) == 0) sh[threadIdx.x>>6] = s;
    __syncthreads();
    if (threadIdx.x == 0)
        out[0] = (float)(((sh[0]+sh[1])+(sh[2]+sh[3])) * (1.0/8388608.0));
}

// ==================================================================
extern "C" void kernel_launch(void* const* d_in, const int* in_sizes, int n_in,
                              void* d_out, int out_size, void* d_ws, size_t ws_size,
                              hipStream_t stream)
{
    const float* pred   = (const float*)d_in[0];
    const float* labels = (const float*)d_in[1];
    float* out = (float*)d_out;

    char* ws = (char*)d_ws;
    double* partial = (double*)ws;                  // 16 KB (2048 doubles)
    int*    flags   = (int*)(ws + 16384);           // pass flags
    u64*    edgew   = (u64*)(ws + 32768);           // 1 MB
    u64*    weakw   = edgew + NWORDS;               // 1 MB

    hipMemsetAsync(flags, 0, 64, stream);

    k_sobel_nms<<<1024, 64, 0, stream>>>(labels, (u8*)edgew, (u8*)weakw);

    for (int p = 0; p < 4; ++p)                     // 4 x 8 = 32 dilate steps
        k_hyst<<<256, 256, 0, stream>>>(edgew, weakw, flags, p);

    k_loss<<<2048, 256, 0, stream>>>(pred, edgew, partial);
    k_final<<<1, 256, 0, stream>>>(partial, out);
}

// Round 4
// 69.785 us; speedup vs baseline: 2.3900x; 1.3401x over previous
//
#include <hip/hip_runtime.h>

typedef unsigned long long u64;
typedef unsigned int u32;
typedef unsigned char u8;

#define IMH 512
#define IMW 512
#define NB 32
#define WPI 4096
#define NWORDS (NB*WPI)

#define QZ(v) floorf(fminf(fmaxf((v),0.f),1.f)*255.f)

// ==================================================================
// Kernel 1: register-rolling separable Sobel + NMS, no LDS.
// 1 wave/block; lane owns 4 cols; band = 8 output rows; strip = 256 px.
// grid 4096 = 32 img * 2 strips * 64 bands.
// ==================================================================
#define LOADRAW(Y, V, HL, HR) do { \
    int _yc = (Y); _yc = _yc < 0 ? 0 : (_yc > 511 ? 511 : _yc); \
    const float* _row = img + _yc*IMW; \
    V = *(const float4*)&_row[xb]; \
    if (L0)  HL = *(const float2*)&_row[strip ? (X0-2) : 0]; \
    if (L63) HR = *(const float2*)&_row[strip ? 510 : (X0+256)]; \
} while(0)

#define NMSJ(J, QAm, QA0, QAp, PBm, PB0, PBp, CCm, CC0, CCp) do { \
    float m = PB0; \
    float gx_ = gxP[J], gy_ = gyP[J]; \
    float ax = fabsf(gx_), ay = fabsf(gy_); \
    bool c0_ = ay <  T1f*ax; \
    bool c90 = ay >= T2f*ax; \
    bool c45 = (!c0_) && (!c90) && (gx_*gy_ > 0.f); \
    float n1 = c0_ ? PBp : (c45 ? QAp : (c90 ? CC0 : QAm)); \
    float n2 = c0_ ? PBm : (c45 ? CCm : (c90 ? QA0 : CCp)); \
    if (m >= n1 && m >= n2) { \
        if (m > 100.f) wb |= (1u<<(J)); \
        if (m > 200.f) sb |= (1u<<(J)); \
    } \
} while(0)

#define STEP(Y, VIN, HLIN, HRIN, VNX, HLNX, HRNX, DOLOAD) do { \
    if (DOLOAD) LOADRAW((Y)+1, VNX, HLNX, HRNX); \
    float c0=QZ(VIN.x), c1=QZ(VIN.y), c2=QZ(VIN.z), c3=QZ(VIN.w); \
    float chl0 = QZ(HLIN.x), chl1 = strip ? QZ(HLIN.y) : QZ(HLIN.x); \
    float chr0 = strip ? QZ(HRIN.y) : QZ(HRIN.x), chr1 = QZ(HRIN.y); \
    float qn0=rP[0]+c0, qn1=rP[1]+c1, qn2=rP[2]+c2, qn3=rP[3]+c3; \
    float ql0=hPl0+chl0, ql1=hPl1+chl1, qr0=hPr0+chr0, qr1=hPr1+chr1; \
    float t1_0=qP[0]+qn0, t1_1=qP[1]+qn1, t1_2=qP[2]+qn2, t1_3=qP[3]+qn3; \
    float t2_0=qn0-qP[0], t2_1=qn1-qP[1], t2_2=qn2-qP[2], t2_3=qn3-qP[3]; \
    float t1l0=qPl0+ql0, t2l0=ql0-qPl0, t1l1=qPl1+ql1, t2l1=ql1-qPl1; \
    float t1r0=qPr0+qr0, t2r0=qr0-qPr0, t1r1=qPr1+qr1, t2r1=qr1-qPr1; \
    float su1=__shfl_up(t1_3,1), su2=__shfl_up(t2_3,1); \
    float sd1=__shfl_down(t1_0,1), sd2=__shfl_down(t2_0,1); \
    float t1m = L0 ? t1l1 : su1, t2m = L0 ? t2l1 : su2; \
    float t1p = L63 ? t1r0 : sd1, t2p = L63 ? t2r0 : sd2; \
    const int ry = (Y)-1; \
    const bool rok = (ry >= 0) && (ry <= 511); \
    float gxc0 = t1_1-t1m,  gyc0 = t2m +2.f*t2_0+t2_1; \
    float gxc1 = t1_2-t1_0, gyc1 = t2_0+2.f*t2_1+t2_2; \
    float gxc2 = t1_3-t1_1, gyc2 = t2_1+2.f*t2_2+t2_3; \
    float gxc3 = t1p -t1_2, gyc3 = t2_2+2.f*t2_3+t2p; \
    float mc0 = rok ? fabsf(gxc0)+fabsf(gyc0) : 0.f; \
    float mc1 = rok ? fabsf(gxc1)+fabsf(gyc1) : 0.f; \
    float mc2 = rok ? fabsf(gxc2)+fabsf(gyc2) : 0.f; \
    float mc3 = rok ? fabsf(gxc3)+fabsf(gyc3) : 0.f; \
    float gxl = t1_0-t1l0, gyl = t2l0+2.f*t2l1+t2_0; \
    float gxr = t1r1-t1_3, gyr = t2_3+2.f*t2r0+t2r1; \
    float mlh = (rok && strip!=0) ? fabsf(gxl)+fabsf(gyl) : 0.f; \
    float mrh = (rok && strip!=1) ? fabsf(gxr)+fabsf(gyr) : 0.f; \
    float sum_ = __shfl_up(mc3,1), sdm_ = __shfl_down(mc0,1); \
    float mCL = L0 ? mlh : sum_; \
    float mCR = L63 ? mrh : sdm_; \
    if ((Y) >= y0+2) { \
        u32 sb=0, wb=0; \
        NMSJ(0, mgQL,  mgQ[0], mgQ[1], mgPL,  mgP[0], mgP[1], mCL, mc0, mc1); \
        NMSJ(1, mgQ[0],mgQ[1], mgQ[2], mgP[0],mgP[1], mgP[2], mc0, mc1, mc2); \
        NMSJ(2, mgQ[1],mgQ[2], mgQ[3], mgP[1],mgP[2], mgP[3], mc1, mc2, mc3); \
        NMSJ(3, mgQ[2],mgQ[3], mgQR,   mgP[2],mgP[3], mgPR,   mc2, mc3, mCR); \
        u32 pk = sb | (wb<<8); \
        u32 oth = __shfl_xor(pk, 1); \
        if (!(lane & 1)) { \
            size_t bix = ((size_t)(bimg*IMH + ((Y)-2)))*64 + strip*32 + (lane>>1); \
            edgeb[bix] = (u8)((sb & 0xFu) | ((oth & 0xFu) << 4)); \
            weakb[bix] = (u8)(((pk>>8) & 0xFu) | (((oth>>8) & 0xFu) << 4)); \
        } \
    } \
    mgQ[0]=mgP[0]; mgQ[1]=mgP[1]; mgQ[2]=mgP[2]; mgQ[3]=mgP[3]; \
    mgQL=mgPL; mgQR=mgPR; \
    mgP[0]=mc0; mgP[1]=mc1; mgP[2]=mc2; mgP[3]=mc3; \
    mgPL=mCL; mgPR=mCR; \
    gxP[0]=gxc0; gxP[1]=gxc1; gxP[2]=gxc2; gxP[3]=gxc3; \
    gyP[0]=gyc0; gyP[1]=gyc1; gyP[2]=gyc2; gyP[3]=gyc3; \
    qP[0]=qn0; qP[1]=qn1; qP[2]=qn2; qP[3]=qn3; \
    qPl0=ql0; qPl1=ql1; qPr0=qr0; qPr1=qr1; \
    rP[0]=c0; rP[1]=c1; rP[2]=c2; rP[3]=c3; \
    hPl0=chl0; hPl1=chl1; hPr0=chr0; hPr1=chr1; \
} while(0)

__global__ __launch_bounds__(64) void k_sobel_nms(
    const float* __restrict__ labels,
    u8* __restrict__ edgeb,
    u8* __restrict__ weakb,
    int* __restrict__ flags)
{
    const int lane  = threadIdx.x;
    const int bx    = blockIdx.x;
    if (bx == 0 && lane < 16) flags[lane] = 0;   // zero pass flags (pre-hyst)
    const int bimg  = bx >> 7;                   // 128 blocks per image
    const int strip = bx & 1;
    const int band  = (bx >> 1) & 63;
    const int X0 = strip*256;
    const int y0 = band*8;
    const int xb = X0 + 4*lane;
    const bool L0 = (lane==0), L63 = (lane==63);
    const float* img = labels + (size_t)bimg*(IMH*IMW);
    const float T1f = 0.41421356237309503f;   // tan 22.5
    const float T2f = 2.4142135623730951f;    // tan 67.5

    // rolling state
    float rP[4];                   // prev row quantized px
    float hPl0,hPl1,hPr0,hPr1;     // prev row halo px
    float qP[4];                   // vertical pair-sum boundary (y-2,y-1)
    float qPl0,qPl1,qPr0,qPr1;
    float mgQ[4], mgP[4];          // mag rows y-3, y-2
    float mgQL,mgQR,mgPL,mgPR;
    float gxP[4], gyP[4];          // gradients at row y-2

    float4 vA, vB;
    float2 hlA = make_float2(0.f,0.f), hlB = make_float2(0.f,0.f);
    float2 hrA = make_float2(0.f,0.f), hrB = make_float2(0.f,0.f);

    // warmup: rows y0-2, y0-1
    LOADRAW(y0-2, vA, hlA, hrA);
    LOADRAW(y0-1, vB, hlB, hrB);
    {
        float a0=QZ(vA.x), a1=QZ(vA.y), a2=QZ(vA.z), a3=QZ(vA.w);
        float b0=QZ(vB.x), b1=QZ(vB.y), b2=QZ(vB.z), b3=QZ(vB.w);
        qP[0]=a0+b0; qP[1]=a1+b1; qP[2]=a2+b2; qP[3]=a3+b3;
        rP[0]=b0; rP[1]=b1; rP[2]=b2; rP[3]=b3;
        float al0 = QZ(hlA.x), al1 = strip ? QZ(hlA.y) : QZ(hlA.x);
        float ar0 = strip ? QZ(hrA.y) : QZ(hrA.x), ar1 = QZ(hrA.y);
        hPl0 = QZ(hlB.x); hPl1 = strip ? QZ(hlB.y) : QZ(hlB.x);
        hPr0 = strip ? QZ(hrB.y) : QZ(hrB.x); hPr1 = QZ(hrB.y);
        qPl0 = al0 + hPl0; qPl1 = al1 + hPl1;
        qPr0 = ar0 + hPr0; qPr1 = ar1 + hPr1;
    }
#pragma unroll
    for (int j=0;j<4;++j) { mgQ[j]=0.f; mgP[j]=0.f; gxP[j]=0.f; gyP[j]=0.f; }
    mgQL=mgQR=mgPL=mgPR=0.f;

    // prime row y0
    LOADRAW(y0, vA, hlA, hrA);

#pragma unroll 1
    for (int y = y0; y < y0+10; y += 2) {
        STEP(y,   vA, hlA, hrA, vB, hlB, hrB, (y+1 <= y0+9));
        STEP(y+1, vB, hlB, hrB, vA, hlA, hrA, (y+2 <= y0+9));
    }
}

// ==================================================================
// Kernel 2: hysteresis, 8 dilate iterations per launch inside LDS.
// ==================================================================
#define HROWS 64
#define HHALO 8
#define HLDSR (HROWS + 2*HHALO)   // 80

__device__ inline u64 hz3(u64 l, u64 c, u64 r) {
    return c | (c<<1) | (c>>1) | (l>>63) | (r<<63);
}

__global__ __launch_bounds__(256) void k_hyst(
    u64* __restrict__ edgew,
    const u64* __restrict__ weakw,
    int* __restrict__ flags, int p)
{
    if (p > 0 && flags[p-1] == 0) return;
    __shared__ u64 ed[HLDSR][8];
    __shared__ u64 wk[HLDSR][8];
    const int tid = threadIdx.x;
    const int strip = blockIdx.x & 7, b = blockIdx.x >> 3;
    const int y0 = strip*HROWS;
    u64* ebase = edgew + (size_t)b*WPI;
    const u64* wbase = weakw + (size_t)b*WPI;

    u64 orig[3] = {0,0,0};
#pragma unroll
    for (int k = 0; k < 3; ++k) {
        int w = tid + k*256;
        if (w < HLDSR*8) {
            int r = w >> 3, c = w & 7;
            int gr = y0 - HHALO + r;
            u64 e = 0, ww = 0;
            if (gr >= 0 && gr < IMH) { e = ebase[gr*8+c]; ww = wbase[gr*8+c]; }
            ed[r][c] = e; wk[r][c] = ww;
            orig[k] = e;
        }
    }
    __syncthreads();

    for (int it = 0; it < HHALO; ++it) {
#pragma unroll
        for (int k = 0; k < 3; ++k) {
            int w = tid + k*256;
            if (w < HLDSR*8) {
                int r = w >> 3, c = w & 7;
                u64 cm = ed[r][c];
                u64 lm = (c>0)? ed[r][c-1] : 0, rm = (c<7)? ed[r][c+1] : 0;
                u64 d = hz3(lm, cm, rm);
                if (r > 0) {
                    u64 cu = ed[r-1][c];
                    u64 lu = (c>0)? ed[r-1][c-1] : 0, ru = (c<7)? ed[r-1][c+1] : 0;
                    d |= hz3(lu, cu, ru);
                }
                if (r < HLDSR-1) {
                    u64 cd = ed[r+1][c];
                    u64 ld = (c>0)? ed[r+1][c-1] : 0, rd = (c<7)? ed[r+1][c+1] : 0;
                    d |= hz3(ld, cd, rd);
                }
                ed[r][c] = wk[r][c] & d;
            }
        }
        __syncthreads();
    }

    bool chg = false;
#pragma unroll
    for (int k = 0; k < 3; ++k) {
        int w = tid + k*256;
        if (w < HLDSR*8) {
            int r = w >> 3, c = w & 7;
            if (r >= HHALO && r < HHALO + HROWS) {
                u64 nw = ed[r][c];
                if (nw != orig[k]) {
                    chg = true;
                    ebase[(y0 - HHALO + r)*8 + c] = nw;
                }
            }
        }
    }
    if (chg) flags[p] = 1;
}

// ==================================================================
// Kernel 3: NLL loss, 4 float4-pairs/thread, per-block partials
// ==================================================================
__global__ __launch_bounds__(256) void k_loss(
    const float* __restrict__ pred,
    const u64* __restrict__ edgew,
    double* __restrict__ partial)
{
    const int t = blockIdx.x*256 + threadIdx.x;   // 0..524287
    float acc[4];
#pragma unroll
    for (int k = 0; k < 4; ++k) {
        int g = t + k*524288;                     // 0..2097151
        int b = g >> 16, rem4 = g & 65535;
        const float4 p0 = *(const float4*)&pred[((size_t)(2*b)  <<18) + 4*(size_t)rem4];
        const float4 p1 = *(const float4*)&pred[((size_t)(2*b+1)<<18) + 4*(size_t)rem4];
        u64 wrd = edgew[(b<<12) | (rem4>>4)];
        u32 nib = (u32)(wrd >> ((rem4 & 15)*4)) & 0xFu;
        float d0=p1.x-p0.x, d1=p1.y-p0.y, d2=p1.z-p0.z, d3=p1.w-p0.w;
        float t0_ = (nib&1u) ? -d0 : d0;
        float t1_ = (nib&2u) ? -d1 : d1;
        float t2_ = (nib&4u) ? -d2 : d2;
        float t3_ = (nib&8u) ? -d3 : d3;
        float s0 = fmaxf(t0_,0.f) + __logf(1.f + __expf(-fabsf(t0_)));
        float s1 = fmaxf(t1_,0.f) + __logf(1.f + __expf(-fabsf(t1_)));
        float s2 = fmaxf(t2_,0.f) + __logf(1.f + __expf(-fabsf(t2_)));
        float s3 = fmaxf(t3_,0.f) + __logf(1.f + __expf(-fabsf(t3_)));
        acc[k] = (s0+s1)+(s2+s3);
    }
    double s = ((double)acc[0]+(double)acc[1]) + ((double)acc[2]+(double)acc[3]);
#pragma unroll
    for (int off = 32; off > 0; off >>= 1) s += __shfl_down(s, off);
    __shared__ double sh[4];
    if ((threadIdx.x & 63) == 0) sh[threadIdx.x>>6] = s;
    __syncthreads();
    if (threadIdx.x == 0) partial[blockIdx.x] = (sh[0]+sh[1])+(sh[2]+sh[3]);
}

__global__ __launch_bounds__(256) void k_final(
    const double* __restrict__ partial, float* __restrict__ out)
{
    double s = 0.0;
    for (int i = threadIdx.x; i < 2048; i += 256) s += partial[i];
#pragma unroll
    for (int off = 32; off > 0; off >>= 1) s += __shfl_down(s, off);
    __shared__ double sh[4];
    if ((threadIdx.x & 63) == 0) sh[threadIdx.x>>6] = s;
    __syncthreads();
    if (threadIdx.x == 0)
        out[0] = (float)(((sh[0]+sh[1])+(sh[2]+sh[3])) * (1.0/8388608.0));
}

// ==================================================================
extern "C" void kernel_launch(void* const* d_in, const int* in_sizes, int n_in,
                              void* d_out, int out_size, void* d_ws, size_t ws_size,
                              hipStream_t stream)
{
    const float* pred   = (const float*)d_in[0];
    const float* labels = (const float*)d_in[1];
    float* out = (float*)d_out;

    char* ws = (char*)d_ws;
    double* partial = (double*)ws;                  // 16 KB (2048 doubles)
    int*    flags   = (int*)(ws + 16384);           // pass flags
    u64*    edgew   = (u64*)(ws + 32768);           // 1 MB
    u64*    weakw   = edgew + NWORDS;               // 1 MB

    k_sobel_nms<<<4096, 64, 0, stream>>>(labels, (u8*)edgew, (u8*)weakw, flags);

    for (int p = 0; p < 4; ++p)                     // 4 x 8 = 32 dilate steps
        k_hyst<<<256, 256, 0, stream>>>(edgew, weakw, flags, p);

    k_loss<<<2048, 256, 0, stream>>>(pred, edgew, partial);
    k_final<<<1, 256, 0, stream>>>(partial, out);
}